// Round 1
// baseline (541.474 us; speedup 1.0000x reference)
//
#include <hip/hip_runtime.h>
#include <cstdint>
#include <cstddef>

#define D 256
#define HEADS 8
#define LEVELS 4
#define POINTS 4
#define HD 32
#define NB 2
#define LQ 12240
#define NQ (NB * LQ)   // 24480

// ---------------------------------------------------------------------------
// K1: fused projections.  src(24480x256) @ {w_value(256x256), w_off(256x256),
// w_attn(256x128)}.  value written TRANSPOSED as val_t[n][h][pos][32] so the
// sampling kernel's taps are 128B-contiguous.
// 32 rows/block, 256 threads (16 col-thr x 16 row-thr), 2x4 register tile.
// LDS row stride 260 floats: bank = (r*260+k)%32 -> 4 distinct banks across
// the 4 row-groups in a wave -> conflict-free broadcast reads.
// ---------------------------------------------------------------------------
__global__ __launch_bounds__(256) void proj_kernel(
    const float* __restrict__ src,
    const float* __restrict__ w_value, const float* __restrict__ b_value,
    const float* __restrict__ w_off,   const float* __restrict__ b_off,
    const float* __restrict__ w_attn,  const float* __restrict__ b_attn,
    float* __restrict__ val_t, float* __restrict__ off_raw,
    float* __restrict__ attn_raw)
{
    __shared__ float lds[32][260];
    const int tid = threadIdx.x;
    const int q0  = blockIdx.x * 32;

    // stage src tile: 32 rows x 64 float4, coalesced
#pragma unroll
    for (int p = 0; p < 8; ++p) {
        int idx = p * 256 + tid;
        int r = idx >> 6, k4 = idx & 63;
        float4 v = *(const float4*)(src + (size_t)(q0 + r) * D + k4 * 4);
        *(float4*)&lds[r][k4 * 4] = v;
    }
    __syncthreads();

    const int tx = tid & 15, ty = tid >> 4;
    const int r0 = ty * 2;

    for (int t = 0; t < 10; ++t) {
        const float* Wp; const float* bp; int outw, cbase;
        if (t < 4)      { Wp = w_value; bp = b_value; outw = 256; cbase = t * 64; }
        else if (t < 8) { Wp = w_off;   bp = b_off;   outw = 256; cbase = (t - 4) * 64; }
        else            { Wp = w_attn;  bp = b_attn;  outw = 128; cbase = (t - 8) * 64; }
        const int c = cbase + tx * 4;

        float acc0[4] = {0.f, 0.f, 0.f, 0.f};
        float acc1[4] = {0.f, 0.f, 0.f, 0.f};

        for (int k4 = 0; k4 < 64; ++k4) {
            float4 a0 = *(const float4*)&lds[r0][k4 * 4];
            float4 a1 = *(const float4*)&lds[r0 + 1][k4 * 4];
            const float* wrow = Wp + (size_t)(k4 * 4) * outw + c;
            float4 b0 = *(const float4*)(wrow);
            float4 b1 = *(const float4*)(wrow + outw);
            float4 b2 = *(const float4*)(wrow + 2 * outw);
            float4 b3 = *(const float4*)(wrow + 3 * outw);
#define FMA4(ACC, AS, BV) ACC[0] += (AS)*(BV).x; ACC[1] += (AS)*(BV).y; \
                          ACC[2] += (AS)*(BV).z; ACC[3] += (AS)*(BV).w;
            FMA4(acc0, a0.x, b0) FMA4(acc0, a0.y, b1)
            FMA4(acc0, a0.z, b2) FMA4(acc0, a0.w, b3)
            FMA4(acc1, a1.x, b0) FMA4(acc1, a1.y, b1)
            FMA4(acc1, a1.z, b2) FMA4(acc1, a1.w, b3)
#undef FMA4
        }

#pragma unroll
        for (int i = 0; i < 2; ++i) {
            const float* accp = i ? acc1 : acc0;
            int qg = q0 + r0 + i;
            int n  = (qg >= LQ) ? 1 : 0;
            int ql = qg - n * LQ;
#pragma unroll
            for (int jj = 0; jj < 4; ++jj) {
                int j = c + jj;
                float v = accp[jj] + bp[j];
                if (t < 4) {
                    int h = j >> 5, hd = j & 31;
                    val_t[(((size_t)(n * HEADS + h)) * LQ + ql) * HD + hd] = v;
                } else if (t < 8) {
                    off_raw[(size_t)qg * 256 + j] = v;
                } else {
                    attn_raw[(size_t)qg * 128 + j] = v;
                }
            }
        }
    }
}

// ---------------------------------------------------------------------------
// K2: softmax + sampling-locations + bilinear gather + weighted sum.
// One 32-lane group per (n,q,head); lane = channel (0..31).
// Lanes' lp = lane&15 each own one (level,point); width-16 shuffles do the
// softmax and broadcast tap indices/weights to the channel lanes.
// NOTE: `sampled` aliases `off_raw` (reads of off precede the single write by
// data dependence within the lockstep wave) -> no __restrict__ on either.
// ---------------------------------------------------------------------------
__global__ __launch_bounds__(256) void sample_kernel(
    const float* __restrict__ ref_pts,
    const float* __restrict__ val_t,
    const float* off_raw,
    const float* __restrict__ attn_raw,
    float* sampled)
{
    const int g    = blockIdx.x * 8 + (threadIdx.x >> 5);
    const int lane = threadIdx.x & 31;
    const int qg = g >> 3, h = g & 7;
    const int n  = (qg >= LQ) ? 1 : 0;
    const int lp = lane & 15;
    const int l  = lp >> 2;

    // softmax over 16 (level,point) logits of this head
    float a = attn_raw[(size_t)qg * 128 + h * 16 + lp];
    float m = a;
#pragma unroll
    for (int s = 8; s; s >>= 1) m = fmaxf(m, __shfl_xor(m, s, 16));
    float e = __expf(a - m);
    float ssum = e;
#pragma unroll
    for (int s = 8; s; s >>= 1) ssum += __shfl_xor(ssum, s, 16);
    float aw = e / ssum;

    // sampling location for this lane's (l,p)
    float ox = off_raw[(size_t)qg * 256 + h * 32 + lp * 2 + 0];
    float oy = off_raw[(size_t)qg * 256 + h * 32 + lp * 2 + 1];
    float rx = ref_pts[(qg * 4 + l) * 2 + 0];
    float ry = ref_pts[(qg * 4 + l) * 2 + 1];

    const int Wi = 96 >> l;       // 96,48,24,12 (square levels)
    const int Hi = Wi;
    const int s0 = (l > 0 ? 9216 : 0) + (l > 1 ? 2304 : 0) + (l > 2 ? 576 : 0);
    const float Wf = (float)Wi, Hf = (float)Hi;

    float x = (rx + ox / Wf) * Wf - 0.5f;
    float y = (ry + oy / Hf) * Hf - 0.5f;
    float x0f = floorf(x), y0f = floorf(y);
    float lx = x - x0f, ly = y - y0f;
    int x0 = (int)x0f, y0 = (int)y0f;

    int   idxv[4];
    float wtv[4];
#pragma unroll
    for (int tdy = 0; tdy < 2; ++tdy) {
#pragma unroll
        for (int tdx = 0; tdx < 2; ++tdx) {
            int xi = x0 + tdx, yi = y0 + tdy;
            bool valid = (xi >= 0) && (xi < Wi) && (yi >= 0) && (yi < Hi);
            int xc = min(max(xi, 0), Wi - 1);
            int yc = min(max(yi, 0), Hi - 1);
            int tnum = tdy * 2 + tdx;
            idxv[tnum] = (s0 + yc * Wi + xc) * HD;
            float wx = tdx ? lx : 1.f - lx;
            float wy = tdy ? ly : 1.f - ly;
            wtv[tnum] = aw * wx * wy * (valid ? 1.f : 0.f);
        }
    }

    const float* plane = val_t + (size_t)(n * HEADS + h) * ((size_t)LQ * HD);
    float o = 0.f;
#pragma unroll
    for (int p = 0; p < 16; ++p) {
        int   i0 = __shfl(idxv[0], p, 16);
        int   i1 = __shfl(idxv[1], p, 16);
        int   i2 = __shfl(idxv[2], p, 16);
        int   i3 = __shfl(idxv[3], p, 16);
        float w0 = __shfl(wtv[0], p, 16);
        float w1 = __shfl(wtv[1], p, 16);
        float w2 = __shfl(wtv[2], p, 16);
        float w3 = __shfl(wtv[3], p, 16);
        o += w0 * plane[i0 + lane] + w1 * plane[i1 + lane]
           + w2 * plane[i2 + lane] + w3 * plane[i3 + lane];
    }
    sampled[(size_t)qg * 256 + h * 32 + lane] = o;
}

// ---------------------------------------------------------------------------
// K3: out = sampled @ w_out + b_out;  x = src + out;  LayerNorm(x)*gamma+beta.
// 16 rows/block, thread = output column.  LDS broadcast reads (all 256
// threads read the same st[r][k] -> bank broadcast, conflict-free).
// ---------------------------------------------------------------------------
__global__ __launch_bounds__(256) void out_ln_kernel(
    const float* __restrict__ sampled, const float* __restrict__ src,
    const float* __restrict__ w_out,   const float* __restrict__ b_out,
    const float* __restrict__ gamma,   const float* __restrict__ beta,
    float* __restrict__ out)
{
    __shared__ float st[16][256];
    __shared__ float xt[16][257];
    __shared__ float mu_s[16], rs_s[16];
    const int tid = threadIdx.x;
    const int q0  = blockIdx.x * 16;

#pragma unroll
    for (int r = 0; r < 16; ++r)
        st[r][tid] = sampled[(size_t)(q0 + r) * 256 + tid];
    __syncthreads();

    float acc[16];
#pragma unroll
    for (int r = 0; r < 16; ++r) acc[r] = 0.f;

    for (int k4 = 0; k4 < 64; ++k4) {
        float wk0 = w_out[(size_t)(k4 * 4 + 0) * 256 + tid];
        float wk1 = w_out[(size_t)(k4 * 4 + 1) * 256 + tid];
        float wk2 = w_out[(size_t)(k4 * 4 + 2) * 256 + tid];
        float wk3 = w_out[(size_t)(k4 * 4 + 3) * 256 + tid];
#pragma unroll
        for (int r = 0; r < 16; ++r) {
            float4 sv = *(const float4*)&st[r][k4 * 4];
            acc[r] += sv.x * wk0 + sv.y * wk1 + sv.z * wk2 + sv.w * wk3;
        }
    }

    float bo = b_out[tid];
#pragma unroll
    for (int r = 0; r < 16; ++r)
        xt[r][tid] = acc[r] + bo + src[(size_t)(q0 + r) * 256 + tid];
    __syncthreads();

    const int wv = tid >> 6, lane = tid & 63;
#pragma unroll
    for (int rr = 0; rr < 4; ++rr) {
        int r = wv * 4 + rr;
        float s = 0.f, s2 = 0.f;
#pragma unroll
        for (int c = 0; c < 4; ++c) {
            float v = xt[r][lane + c * 64];
            s += v; s2 += v * v;
        }
#pragma unroll
        for (int off = 32; off; off >>= 1) {
            s  += __shfl_xor(s, off);
            s2 += __shfl_xor(s2, off);
        }
        if (lane == 0) {
            float mu  = s * (1.f / 256.f);
            float var = s2 * (1.f / 256.f) - mu * mu;
            mu_s[r] = mu;
            rs_s[r] = rsqrtf(var + 1e-5f);
        }
    }
    __syncthreads();

    float gm = gamma[tid], be = beta[tid];
#pragma unroll
    for (int r = 0; r < 16; ++r) {
        float xv = xt[r][tid];
        out[(size_t)(q0 + r) * 256 + tid] = (xv - mu_s[r]) * rs_s[r] * gm + be;
    }
}

// ---------------------------------------------------------------------------
extern "C" void kernel_launch(void* const* d_in, const int* in_sizes, int n_in,
                              void* d_out, int out_size, void* d_ws, size_t ws_size,
                              hipStream_t stream)
{
    const float* src     = (const float*)d_in[0];
    const float* refp    = (const float*)d_in[1];
    // d_in[2] spatial_shapes (int64), d_in[3] level_start_index (int64): compile-time constants
    const float* w_value = (const float*)d_in[4];
    const float* b_value = (const float*)d_in[5];
    const float* w_off   = (const float*)d_in[6];
    const float* b_off   = (const float*)d_in[7];
    const float* w_attn  = (const float*)d_in[8];
    const float* b_attn  = (const float*)d_in[9];
    const float* w_out   = (const float*)d_in[10];
    const float* b_out   = (const float*)d_in[11];
    const float* gamma   = (const float*)d_in[12];
    const float* beta    = (const float*)d_in[13];

    float* ws       = (float*)d_ws;
    float* val_t    = ws;                    // NB*HEADS*LQ*HD  = 6,266,880 floats
    float* off_raw  = ws + 6266880;          // NQ*256          = 6,266,880 floats
    float* attn_raw = ws + 12533760;         // NQ*128          = 3,133,440 floats
    float* sampled  = off_raw;               // alias (safe: see K2)
    float* out      = (float*)d_out;

    proj_kernel<<<NQ / 32, 256, 0, stream>>>(src, w_value, b_value, w_off, b_off,
                                             w_attn, b_attn, val_t, off_raw, attn_raw);
    sample_kernel<<<NQ, 256, 0, stream>>>(refp, val_t, off_raw, attn_raw, sampled);
    out_ln_kernel<<<NQ / 16, 256, 0, stream>>>(sampled, src, w_out, b_out,
                                               gamma, beta, out);
}

// Round 2
// 319.075 us; speedup vs baseline: 1.6970x; 1.6970x over previous
//
#include <hip/hip_runtime.h>
#include <cstdint>
#include <cstddef>

#define D 256
#define HEADS 8
#define LEVELS 4
#define POINTS 4
#define HD 32
#define NB 2
#define LQ 12240
#define NQ (NB * LQ)   // 24480

typedef __attribute__((ext_vector_type(8))) short bf16x8;
typedef __attribute__((ext_vector_type(4))) float f32x4;

__device__ __forceinline__ ushort f2bf(float f) {
    union { float f; uint32_t u; } c; c.f = f;
    uint32_t u = c.u;
    uint32_t r = (u + 0x7fffu + ((u >> 16) & 1u)) >> 16;   // RNE, finite inputs
    return (ushort)r;
}
__device__ __forceinline__ float bf2f(ushort b) {
    union { uint32_t u; float f; } c; c.u = ((uint32_t)b) << 16;
    return c.f;
}

// ---------------------------------------------------------------------------
// K0: weight/bias conversion.
// B_pack[n][k] bf16, n: 0..255=w_value cols, 256..511=w_off, 512..639=w_attn.
// w_out_t[n][k] bf16.  b_pack[640] fp32.
// ---------------------------------------------------------------------------
__global__ __launch_bounds__(256) void conv_kernel(
    const float* __restrict__ w_value, const float* __restrict__ w_off,
    const float* __restrict__ w_attn,  const float* __restrict__ b_value,
    const float* __restrict__ b_off,   const float* __restrict__ b_attn,
    const float* __restrict__ w_out,
    ushort* __restrict__ B_pack, ushort* __restrict__ w_out_t,
    float* __restrict__ b_pack)
{
    const int b = blockIdx.x, k = threadIdx.x;
    if (b < 640) {
        float v;
        if (b < 256)      v = w_value[(size_t)k * 256 + b];
        else if (b < 512) v = w_off[(size_t)k * 256 + (b - 256)];
        else              v = w_attn[(size_t)k * 128 + (b - 512)];
        B_pack[(size_t)b * 256 + k] = f2bf(v);
    } else if (b < 896) {
        int n = b - 640;
        w_out_t[(size_t)n * 256 + k] = f2bf(w_out[(size_t)k * 256 + n]);
    } else if (b == 896) {
        b_pack[k] = b_value[k];
    } else if (b == 897) {
        b_pack[256 + k] = b_off[k];
    } else {
        if (k < 128) b_pack[512 + k] = b_attn[k];
    }
}

// ---------------------------------------------------------------------------
// K1: fused projections via MFMA.  M=24480, N=640, K=256.
// One block per 64-row M-tile; A staged once (fp32->bf16); loop 10 N-tiles
// staging B (L2-resident).  A-fragments cached in registers for the whole
// N-loop.  LDS stride 264 ushort (528B): each 8-lane group of a ds_read_b128
// covers all 32 banks once -> conflict-free.
// ---------------------------------------------------------------------------
__global__ __launch_bounds__(256) void proj_gemm(
    const float* __restrict__ src, const ushort* __restrict__ B_pack,
    const float* __restrict__ b_pack,
    ushort* __restrict__ val_t, float* __restrict__ off_raw,
    float* __restrict__ attn_raw)
{
    __shared__ ushort Abuf[64][264];
    __shared__ ushort Bbuf[64][264];
    const int tid = threadIdx.x;
    const int m0  = blockIdx.x * 64;

    // stage A: 64 rows x 256 k, fp32 -> bf16
#pragma unroll
    for (int it = 0; it < 16; ++it) {
        int r = it * 4 + (tid >> 6), k4 = tid & 63;
        int row = m0 + r;
        float4 v = {0.f, 0.f, 0.f, 0.f};
        if (row < NQ) v = *(const float4*)(src + (size_t)row * 256 + k4 * 4);
        ushort4 o; o.x = f2bf(v.x); o.y = f2bf(v.y); o.z = f2bf(v.z); o.w = f2bf(v.w);
        *(ushort4*)&Abuf[r][k4 * 4] = o;
    }
    __syncthreads();

    const int wv = tid >> 6, lane = tid & 63;
    const int quad = lane >> 4, ln = lane & 15;

    bf16x8 af[8];
#pragma unroll
    for (int s = 0; s < 8; ++s)
        af[s] = *(const bf16x8*)&Abuf[wv * 16 + ln][s * 32 + quad * 8];

    for (int by = 0; by < 10; ++by) {
        __syncthreads();
#pragma unroll
        for (int it = 0; it < 16; ++it) {
            int n = it * 4 + (tid >> 6), kc = tid & 63;
            *(ushort4*)&Bbuf[n][kc * 4] =
                *(const ushort4*)(B_pack + ((size_t)(by * 64 + n)) * 256 + kc * 4);
        }
        __syncthreads();

        f32x4 acc[4] = {{0,0,0,0},{0,0,0,0},{0,0,0,0},{0,0,0,0}};
#pragma unroll
        for (int s = 0; s < 8; ++s) {
#pragma unroll
            for (int t = 0; t < 4; ++t) {
                bf16x8 bfr = *(const bf16x8*)&Bbuf[t * 16 + ln][s * 32 + quad * 8];
                acc[t] = __builtin_amdgcn_mfma_f32_16x16x32_bf16(af[s], bfr, acc[t], 0, 0, 0);
            }
        }

#pragma unroll
        for (int t = 0; t < 4; ++t) {
            int n_g = by * 64 + t * 16 + ln;
            float bias = b_pack[n_g];
#pragma unroll
            for (int reg = 0; reg < 4; ++reg) {
                int row = m0 + wv * 16 + quad * 4 + reg;
                if (row < NQ) {
                    float v = acc[t][reg] + bias;
                    if (n_g < 256) {
                        int h = n_g >> 5, hd = n_g & 31;
                        int nb = row >= LQ; int ql = row - nb * LQ;
                        val_t[(((size_t)(nb * 8 + h)) * LQ + ql) * 32 + hd] = f2bf(v);
                    } else if (n_g < 512) {
                        off_raw[(size_t)row * 256 + (n_g - 256)] = v;
                    } else {
                        attn_raw[(size_t)row * 128 + (n_g - 512)] = v;
                    }
                }
            }
        }
    }
}

// ---------------------------------------------------------------------------
// K2: softmax + sampling locations + bilinear gather (bf16 value).
// One 32-lane group per (n,q,head); lane = channel.
// `sampled` (bf16) aliases `attn_raw` (fp32) byte-exactly per (q,h) group:
// each group overwrites exactly the region it read, write data-depends on
// the read -> safe.  No __restrict__ on those params.
// ---------------------------------------------------------------------------
__global__ __launch_bounds__(256) void sample_kernel(
    const float* __restrict__ ref_pts,
    const ushort* __restrict__ val_t,
    const float* __restrict__ off_raw,
    const float* attn_raw,
    ushort* sampled)
{
    const int g    = blockIdx.x * 8 + (threadIdx.x >> 5);
    const int lane = threadIdx.x & 31;
    const int qg = g >> 3, h = g & 7;
    const int n  = (qg >= LQ) ? 1 : 0;
    const int lp = lane & 15;
    const int l  = lp >> 2;

    // softmax over 16 (level,point) logits of this head
    float a = attn_raw[(size_t)qg * 128 + h * 16 + lp];
    float m = a;
#pragma unroll
    for (int s = 8; s; s >>= 1) m = fmaxf(m, __shfl_xor(m, s, 16));
    float e = __expf(a - m);
    float ssum = e;
#pragma unroll
    for (int s = 8; s; s >>= 1) ssum += __shfl_xor(ssum, s, 16);
    float aw = e / ssum;

    float ox = off_raw[(size_t)qg * 256 + h * 32 + lp * 2 + 0];
    float oy = off_raw[(size_t)qg * 256 + h * 32 + lp * 2 + 1];
    float rx = ref_pts[(qg * 4 + l) * 2 + 0];
    float ry = ref_pts[(qg * 4 + l) * 2 + 1];

    const int Wi = 96 >> l;
    const int Hi = Wi;
    const int s0 = (l > 0 ? 9216 : 0) + (l > 1 ? 2304 : 0) + (l > 2 ? 576 : 0);
    const float Wf = (float)Wi, Hf = (float)Hi;

    float x = (rx + ox / Wf) * Wf - 0.5f;
    float y = (ry + oy / Hf) * Hf - 0.5f;
    float x0f = floorf(x), y0f = floorf(y);
    float lx = x - x0f, ly = y - y0f;
    int x0 = (int)x0f, y0 = (int)y0f;

    int   idxv[4];
    float wtv[4];
#pragma unroll
    for (int tdy = 0; tdy < 2; ++tdy) {
#pragma unroll
        for (int tdx = 0; tdx < 2; ++tdx) {
            int xi = x0 + tdx, yi = y0 + tdy;
            bool valid = (xi >= 0) && (xi < Wi) && (yi >= 0) && (yi < Hi);
            int xc = min(max(xi, 0), Wi - 1);
            int yc = min(max(yi, 0), Hi - 1);
            int tnum = tdy * 2 + tdx;
            idxv[tnum] = (s0 + yc * Wi + xc) * HD;
            float wx = tdx ? lx : 1.f - lx;
            float wy = tdy ? ly : 1.f - ly;
            wtv[tnum] = aw * wx * wy * (valid ? 1.f : 0.f);
        }
    }

    const ushort* plane = val_t + (size_t)(n * HEADS + h) * ((size_t)LQ * HD);
    float o = 0.f;
#pragma unroll
    for (int p = 0; p < 16; ++p) {
        int   i0 = __shfl(idxv[0], p, 16);
        int   i1 = __shfl(idxv[1], p, 16);
        int   i2 = __shfl(idxv[2], p, 16);
        int   i3 = __shfl(idxv[3], p, 16);
        float w0 = __shfl(wtv[0], p, 16);
        float w1 = __shfl(wtv[1], p, 16);
        float w2 = __shfl(wtv[2], p, 16);
        float w3 = __shfl(wtv[3], p, 16);
        o += w0 * bf2f(plane[i0 + lane]) + w1 * bf2f(plane[i1 + lane])
           + w2 * bf2f(plane[i2 + lane]) + w3 * bf2f(plane[i3 + lane]);
    }
    sampled[(size_t)qg * 256 + h * 32 + lane] = f2bf(o);
}

// ---------------------------------------------------------------------------
// K3a: out = sampled @ w_out + b_out + src  -> x (fp32).  MFMA, same skeleton
// as proj_gemm with 4 N-tiles.
// ---------------------------------------------------------------------------
__global__ __launch_bounds__(256) void out_gemm(
    const ushort* __restrict__ sampled, const ushort* __restrict__ w_out_t,
    const float* __restrict__ b_out,    const float* __restrict__ src,
    float* __restrict__ x)
{
    __shared__ ushort Abuf[64][264];
    __shared__ ushort Bbuf[64][264];
    const int tid = threadIdx.x;
    const int m0  = blockIdx.x * 64;

#pragma unroll
    for (int it = 0; it < 16; ++it) {
        int r = it * 4 + (tid >> 6), kc = tid & 63;
        int row = m0 + r;
        ushort4 v = {0, 0, 0, 0};
        if (row < NQ) v = *(const ushort4*)(sampled + (size_t)row * 256 + kc * 4);
        *(ushort4*)&Abuf[r][kc * 4] = v;
    }
    __syncthreads();

    const int wv = tid >> 6, lane = tid & 63;
    const int quad = lane >> 4, ln = lane & 15;

    bf16x8 af[8];
#pragma unroll
    for (int s = 0; s < 8; ++s)
        af[s] = *(const bf16x8*)&Abuf[wv * 16 + ln][s * 32 + quad * 8];

    for (int by = 0; by < 4; ++by) {
        __syncthreads();
#pragma unroll
        for (int it = 0; it < 16; ++it) {
            int nn = it * 4 + (tid >> 6), kc = tid & 63;
            *(ushort4*)&Bbuf[nn][kc * 4] =
                *(const ushort4*)(w_out_t + ((size_t)(by * 64 + nn)) * 256 + kc * 4);
        }
        __syncthreads();

        f32x4 acc[4] = {{0,0,0,0},{0,0,0,0},{0,0,0,0},{0,0,0,0}};
#pragma unroll
        for (int s = 0; s < 8; ++s) {
#pragma unroll
            for (int t = 0; t < 4; ++t) {
                bf16x8 bfr = *(const bf16x8*)&Bbuf[t * 16 + ln][s * 32 + quad * 8];
                acc[t] = __builtin_amdgcn_mfma_f32_16x16x32_bf16(af[s], bfr, acc[t], 0, 0, 0);
            }
        }

#pragma unroll
        for (int t = 0; t < 4; ++t) {
            int n_g = by * 64 + t * 16 + ln;
            float bias = b_out[n_g];
#pragma unroll
            for (int reg = 0; reg < 4; ++reg) {
                int row = m0 + wv * 16 + quad * 4 + reg;
                if (row < NQ) {
                    x[(size_t)row * 256 + n_g] =
                        acc[t][reg] + bias + src[(size_t)row * 256 + n_g];
                }
            }
        }
    }
}

// ---------------------------------------------------------------------------
// K3b: LayerNorm.  One wave per row, float4 per lane.
// ---------------------------------------------------------------------------
__global__ __launch_bounds__(256) void ln_kernel(
    const float* __restrict__ x, const float* __restrict__ gamma,
    const float* __restrict__ beta, float* __restrict__ out)
{
    const int row  = blockIdx.x * 4 + (threadIdx.x >> 6);
    const int lane = threadIdx.x & 63;
    float4 v = *(const float4*)(x + (size_t)row * 256 + lane * 4);
    float s  = v.x + v.y + v.z + v.w;
    float s2 = v.x * v.x + v.y * v.y + v.z * v.z + v.w * v.w;
#pragma unroll
    for (int o = 32; o; o >>= 1) {
        s  += __shfl_xor(s, o);
        s2 += __shfl_xor(s2, o);
    }
    float mu  = s * (1.f / 256.f);
    float var = s2 * (1.f / 256.f) - mu * mu;
    float rs  = rsqrtf(var + 1e-5f);
    float4 g = *(const float4*)(gamma + lane * 4);
    float4 b = *(const float4*)(beta + lane * 4);
    float4 o4;
    o4.x = (v.x - mu) * rs * g.x + b.x;
    o4.y = (v.y - mu) * rs * g.y + b.y;
    o4.z = (v.z - mu) * rs * g.z + b.z;
    o4.w = (v.w - mu) * rs * g.w + b.w;
    *(float4*)(out + (size_t)row * 256 + lane * 4) = o4;
}

// ---------------------------------------------------------------------------
extern "C" void kernel_launch(void* const* d_in, const int* in_sizes, int n_in,
                              void* d_out, int out_size, void* d_ws, size_t ws_size,
                              hipStream_t stream)
{
    const float* src     = (const float*)d_in[0];
    const float* refp    = (const float*)d_in[1];
    const float* w_value = (const float*)d_in[4];
    const float* b_value = (const float*)d_in[5];
    const float* w_off   = (const float*)d_in[6];
    const float* b_off   = (const float*)d_in[7];
    const float* w_attn  = (const float*)d_in[8];
    const float* b_attn  = (const float*)d_in[9];
    const float* w_out   = (const float*)d_in[10];
    const float* b_out   = (const float*)d_in[11];
    const float* gamma   = (const float*)d_in[12];
    const float* beta    = (const float*)d_in[13];

    char* ws = (char*)d_ws;
    ushort* val_t    = (ushort*)(ws);                       // 12,533,760 B
    float*  off_raw  = (float*) (ws + 12533760);            // 25,067,520 B
    float*  attn_raw = (float*) (ws + 37601280);            // 12,533,760 B
    ushort* sampled  = (ushort*)(ws + 37601280);            // alias of attn_raw (safe: K2)
    ushort* B_pack   = (ushort*)(ws + 50135040);            //    327,680 B
    ushort* w_out_t  = (ushort*)(ws + 50462720);            //    131,072 B
    float*  b_pack   = (float*) (ws + 50593792);            //      2,560 B
    float*  x        = off_raw;                             // alias (off_raw dead after K2)
    float*  out      = (float*)d_out;

    conv_kernel<<<899, 256, 0, stream>>>(w_value, w_off, w_attn, b_value, b_off,
                                         b_attn, w_out, B_pack, w_out_t, b_pack);
    proj_gemm<<<383, 256, 0, stream>>>(src, B_pack, b_pack, val_t, off_raw, attn_raw);
    sample_kernel<<<NQ, 256, 0, stream>>>(refp, val_t, off_raw, attn_raw, sampled);
    out_gemm<<<383, 256, 0, stream>>>(sampled, w_out_t, b_out, src, x);
    ln_kernel<<<NQ / 4, 256, 0, stream>>>(x, gamma, beta, out);
}

// Round 3
// 263.343 us; speedup vs baseline: 2.0562x; 1.2116x over previous
//
#include <hip/hip_runtime.h>
#include <cstdint>
#include <cstddef>

#define D 256
#define HEADS 8
#define LEVELS 4
#define POINTS 4
#define HD 32
#define NB 2
#define LQ 12240
#define NQ (NB * LQ)   // 24480

typedef __attribute__((ext_vector_type(8))) short bf16x8;
typedef __attribute__((ext_vector_type(4))) float f32x4;

__device__ __forceinline__ ushort f2bf(float f) {
    union { float f; uint32_t u; } c; c.f = f;
    uint32_t u = c.u;
    uint32_t r = (u + 0x7fffu + ((u >> 16) & 1u)) >> 16;   // RNE, finite inputs
    return (ushort)r;
}

// ---------------------------------------------------------------------------
// K0: weight/bias conversion.
// B_pack[n][k] bf16, n: 0..255=w_value cols, 256..511=w_off, 512..639=w_attn.
// w_out_t[n][k] bf16.  b_pack[640] fp32.
// ---------------------------------------------------------------------------
__global__ __launch_bounds__(256) void conv_kernel(
    const float* __restrict__ w_value, const float* __restrict__ w_off,
    const float* __restrict__ w_attn,  const float* __restrict__ b_value,
    const float* __restrict__ b_off,   const float* __restrict__ b_attn,
    const float* __restrict__ w_out,
    ushort* __restrict__ B_pack, ushort* __restrict__ w_out_t,
    float* __restrict__ b_pack)
{
    const int b = blockIdx.x, k = threadIdx.x;
    if (b < 640) {
        float v;
        if (b < 256)      v = w_value[(size_t)k * 256 + b];
        else if (b < 512) v = w_off[(size_t)k * 256 + (b - 256)];
        else              v = w_attn[(size_t)k * 128 + (b - 512)];
        B_pack[(size_t)b * 256 + k] = f2bf(v);
    } else if (b < 896) {
        int n = b - 640;
        w_out_t[(size_t)n * 256 + k] = f2bf(w_out[(size_t)k * 256 + n]);
    } else if (b == 896) {
        b_pack[k] = b_value[k];
    } else if (b == 897) {
        b_pack[256 + k] = b_off[k];
    } else {
        if (k < 128) b_pack[512 + k] = b_attn[k];
    }
}

// ---------------------------------------------------------------------------
// K1: fused projections via MFMA.  M=24480, N=640, K=256.
// One block per (64-row M-tile, N-half); A staged once (fp32->bf16); loop 5
// N-tiles of 64 staging B (L2-resident).  A-fragments cached in registers.
// LDS stride 264 ushort: conflict-free ds_read_b128.
// gridDim.y=2 splits N -> 766 blocks (vs 383) for occupancy + shorter tail.
// ---------------------------------------------------------------------------
__global__ __launch_bounds__(256) void proj_gemm(
    const float* __restrict__ src, const ushort* __restrict__ B_pack,
    const float* __restrict__ b_pack,
    ushort* __restrict__ val_t, float* __restrict__ off_raw,
    float* __restrict__ attn_raw)
{
    __shared__ ushort Abuf[64][264];
    __shared__ ushort Bbuf[64][264];
    const int tid = threadIdx.x;
    const int m0  = blockIdx.x * 64;

    // stage A: 64 rows x 256 k, fp32 -> bf16
#pragma unroll
    for (int it = 0; it < 16; ++it) {
        int r = it * 4 + (tid >> 6), k4 = tid & 63;
        int row = m0 + r;
        float4 v = {0.f, 0.f, 0.f, 0.f};
        if (row < NQ) v = *(const float4*)(src + (size_t)row * 256 + k4 * 4);
        ushort4 o; o.x = f2bf(v.x); o.y = f2bf(v.y); o.z = f2bf(v.z); o.w = f2bf(v.w);
        *(ushort4*)&Abuf[r][k4 * 4] = o;
    }
    __syncthreads();

    const int wv = tid >> 6, lane = tid & 63;
    const int quad = lane >> 4, ln = lane & 15;

    bf16x8 af[8];
#pragma unroll
    for (int s = 0; s < 8; ++s)
        af[s] = *(const bf16x8*)&Abuf[wv * 16 + ln][s * 32 + quad * 8];

    for (int bi = 0; bi < 5; ++bi) {
        const int by = blockIdx.y * 5 + bi;
        __syncthreads();
#pragma unroll
        for (int it = 0; it < 16; ++it) {
            int n = it * 4 + (tid >> 6), kc = tid & 63;
            *(ushort4*)&Bbuf[n][kc * 4] =
                *(const ushort4*)(B_pack + ((size_t)(by * 64 + n)) * 256 + kc * 4);
        }
        __syncthreads();

        f32x4 acc[4] = {{0,0,0,0},{0,0,0,0},{0,0,0,0},{0,0,0,0}};
#pragma unroll
        for (int s = 0; s < 8; ++s) {
#pragma unroll
            for (int t = 0; t < 4; ++t) {
                bf16x8 bfr = *(const bf16x8*)&Bbuf[t * 16 + ln][s * 32 + quad * 8];
                acc[t] = __builtin_amdgcn_mfma_f32_16x16x32_bf16(af[s], bfr, acc[t], 0, 0, 0);
            }
        }

#pragma unroll
        for (int t = 0; t < 4; ++t) {
            int n_g = by * 64 + t * 16 + ln;
            float bias = b_pack[n_g];
#pragma unroll
            for (int reg = 0; reg < 4; ++reg) {
                int row = m0 + wv * 16 + quad * 4 + reg;
                if (row < NQ) {
                    float v = acc[t][reg] + bias;
                    if (n_g < 256) {
                        int h = n_g >> 5, hd = n_g & 31;
                        int nb = row >= LQ; int ql = row - nb * LQ;
                        val_t[(((size_t)(nb * 8 + h)) * LQ + ql) * 32 + hd] = f2bf(v);
                    } else if (n_g < 512) {
                        off_raw[(size_t)row * 256 + (n_g - 256)] = v;
                    } else {
                        attn_raw[(size_t)row * 128 + (n_g - 512)] = v;
                    }
                }
            }
        }
    }
}

// ---------------------------------------------------------------------------
// K2: softmax + sampling locations + bilinear gather (bf16 value).
// One 16-lane group per (n,q,head); lane ln owns channel pair (2ln, 2ln+1)
// loaded as one u32; lane ln also owns (level,point) ln for the setup phase
// (softmax + location + tap idx/wt) -- a 1:1 mapping, no redistribution.
// Packed-bf16 unpack is free-ish: hi f32 bits = u & 0xffff0000, lo = u << 16.
// `sampled` (bf16, u32-per-lane) aliases `attn_raw` (fp32) byte-exactly per
// group: lane ln reads attn word ln then writes word ln -> safe.
// ---------------------------------------------------------------------------
__global__ __launch_bounds__(256) void sample_kernel(
    const float* __restrict__ ref_pts,
    const ushort* __restrict__ val_t,
    const float* __restrict__ off_raw,
    const float* attn_raw,
    uint32_t* sampled)
{
    const int g  = blockIdx.x * 16 + (threadIdx.x >> 4);
    const int ln = threadIdx.x & 15;
    const int qg = g >> 3, h = g & 7;
    const int n  = (qg >= LQ) ? 1 : 0;
    const int l  = ln >> 2;

    // softmax over 16 (level,point) logits of this head
    float a = attn_raw[(size_t)qg * 128 + h * 16 + ln];
    float m = a;
#pragma unroll
    for (int s = 8; s; s >>= 1) m = fmaxf(m, __shfl_xor(m, s, 16));
    float e = __expf(a - m);
    float ssum = e;
#pragma unroll
    for (int s = 8; s; s >>= 1) ssum += __shfl_xor(ssum, s, 16);
    float aw = e / ssum;

    float ox = off_raw[(size_t)qg * 256 + h * 32 + ln * 2 + 0];
    float oy = off_raw[(size_t)qg * 256 + h * 32 + ln * 2 + 1];
    float rx = ref_pts[(qg * 4 + l) * 2 + 0];
    float ry = ref_pts[(qg * 4 + l) * 2 + 1];

    const int Wi = 96 >> l;
    const int Hi = Wi;
    const int s0 = (l > 0 ? 9216 : 0) + (l > 1 ? 2304 : 0) + (l > 2 ? 576 : 0);
    const float Wf = (float)Wi, Hf = (float)Hi;

    float x = (rx + ox / Wf) * Wf - 0.5f;
    float y = (ry + oy / Hf) * Hf - 0.5f;
    float x0f = floorf(x), y0f = floorf(y);
    float lx = x - x0f, ly = y - y0f;
    int x0 = (int)x0f, y0 = (int)y0f;

    int   idxv[4];   // in u32 units: pos*16
    float wtv[4];
#pragma unroll
    for (int tdy = 0; tdy < 2; ++tdy) {
#pragma unroll
        for (int tdx = 0; tdx < 2; ++tdx) {
            int xi = x0 + tdx, yi = y0 + tdy;
            bool valid = (xi >= 0) && (xi < Wi) && (yi >= 0) && (yi < Hi);
            int xc = min(max(xi, 0), Wi - 1);
            int yc = min(max(yi, 0), Hi - 1);
            int tnum = tdy * 2 + tdx;
            idxv[tnum] = (s0 + yc * Wi + xc) * 16;
            float wx = tdx ? lx : 1.f - lx;
            float wy = tdy ? ly : 1.f - ly;
            wtv[tnum] = aw * wx * wy * (valid ? 1.f : 0.f);
        }
    }

    const uint32_t* plane =
        (const uint32_t*)(val_t + (size_t)(n * HEADS + h) * ((size_t)LQ * HD));
    float olo = 0.f, ohi = 0.f;
#pragma unroll
    for (int p = 0; p < 16; ++p) {
        int   i0 = __shfl(idxv[0], p, 16);
        int   i1 = __shfl(idxv[1], p, 16);
        int   i2 = __shfl(idxv[2], p, 16);
        int   i3 = __shfl(idxv[3], p, 16);
        float w0 = __shfl(wtv[0], p, 16);
        float w1 = __shfl(wtv[1], p, 16);
        float w2 = __shfl(wtv[2], p, 16);
        float w3 = __shfl(wtv[3], p, 16);
        uint32_t u0 = plane[i0 + ln];
        uint32_t u1 = plane[i1 + ln];
        uint32_t u2 = plane[i2 + ln];
        uint32_t u3 = plane[i3 + ln];
        olo += w0 * __uint_as_float(u0 << 16);
        ohi += w0 * __uint_as_float(u0 & 0xffff0000u);
        olo += w1 * __uint_as_float(u1 << 16);
        ohi += w1 * __uint_as_float(u1 & 0xffff0000u);
        olo += w2 * __uint_as_float(u2 << 16);
        ohi += w2 * __uint_as_float(u2 & 0xffff0000u);
        olo += w3 * __uint_as_float(u3 << 16);
        ohi += w3 * __uint_as_float(u3 & 0xffff0000u);
    }
    uint32_t r = ((uint32_t)f2bf(ohi) << 16) | (uint32_t)f2bf(olo);
    sampled[(size_t)qg * 128 + h * 16 + ln] = r;
}

// ---------------------------------------------------------------------------
// K3a: out = sampled @ w_out + b_out + src -> x (fp32).  MFMA; gridDim.y=2
// splits the 4 N-tiles 2+2 -> 766 blocks.
// ---------------------------------------------------------------------------
__global__ __launch_bounds__(256) void out_gemm(
    const ushort* __restrict__ sampled, const ushort* __restrict__ w_out_t,
    const float* __restrict__ b_out,    const float* __restrict__ src,
    float* __restrict__ x)
{
    __shared__ ushort Abuf[64][264];
    __shared__ ushort Bbuf[64][264];
    const int tid = threadIdx.x;
    const int m0  = blockIdx.x * 64;

#pragma unroll
    for (int it = 0; it < 16; ++it) {
        int r = it * 4 + (tid >> 6), kc = tid & 63;
        int row = m0 + r;
        ushort4 v = {0, 0, 0, 0};
        if (row < NQ) v = *(const ushort4*)(sampled + (size_t)row * 256 + kc * 4);
        *(ushort4*)&Abuf[r][kc * 4] = v;
    }
    __syncthreads();

    const int wv = tid >> 6, lane = tid & 63;
    const int quad = lane >> 4, ln = lane & 15;

    bf16x8 af[8];
#pragma unroll
    for (int s = 0; s < 8; ++s)
        af[s] = *(const bf16x8*)&Abuf[wv * 16 + ln][s * 32 + quad * 8];

    for (int bi = 0; bi < 2; ++bi) {
        const int by = blockIdx.y * 2 + bi;
        __syncthreads();
#pragma unroll
        for (int it = 0; it < 16; ++it) {
            int nn = it * 4 + (tid >> 6), kc = tid & 63;
            *(ushort4*)&Bbuf[nn][kc * 4] =
                *(const ushort4*)(w_out_t + ((size_t)(by * 64 + nn)) * 256 + kc * 4);
        }
        __syncthreads();

        f32x4 acc[4] = {{0,0,0,0},{0,0,0,0},{0,0,0,0},{0,0,0,0}};
#pragma unroll
        for (int s = 0; s < 8; ++s) {
#pragma unroll
            for (int t = 0; t < 4; ++t) {
                bf16x8 bfr = *(const bf16x8*)&Bbuf[t * 16 + ln][s * 32 + quad * 8];
                acc[t] = __builtin_amdgcn_mfma_f32_16x16x32_bf16(af[s], bfr, acc[t], 0, 0, 0);
            }
        }

#pragma unroll
        for (int t = 0; t < 4; ++t) {
            int n_g = by * 64 + t * 16 + ln;
            float bias = b_out[n_g];
#pragma unroll
            for (int reg = 0; reg < 4; ++reg) {
                int row = m0 + wv * 16 + quad * 4 + reg;
                if (row < NQ) {
                    x[(size_t)row * 256 + n_g] =
                        acc[t][reg] + bias + src[(size_t)row * 256 + n_g];
                }
            }
        }
    }
}

// ---------------------------------------------------------------------------
// K3b: LayerNorm.  One wave per row, float4 per lane.
// ---------------------------------------------------------------------------
__global__ __launch_bounds__(256) void ln_kernel(
    const float* __restrict__ x, const float* __restrict__ gamma,
    const float* __restrict__ beta, float* __restrict__ out)
{
    const int row  = blockIdx.x * 4 + (threadIdx.x >> 6);
    const int lane = threadIdx.x & 63;
    float4 v = *(const float4*)(x + (size_t)row * 256 + lane * 4);
    float s  = v.x + v.y + v.z + v.w;
    float s2 = v.x * v.x + v.y * v.y + v.z * v.z + v.w * v.w;
#pragma unroll
    for (int o = 32; o; o >>= 1) {
        s  += __shfl_xor(s, o);
        s2 += __shfl_xor(s2, o);
    }
    float mu  = s * (1.f / 256.f);
    float var = s2 * (1.f / 256.f) - mu * mu;
    float rs  = rsqrtf(var + 1e-5f);
    float4 g = *(const float4*)(gamma + lane * 4);
    float4 b = *(const float4*)(beta + lane * 4);
    float4 o4;
    o4.x = (v.x - mu) * rs * g.x + b.x;
    o4.y = (v.y - mu) * rs * g.y + b.y;
    o4.z = (v.z - mu) * rs * g.z + b.z;
    o4.w = (v.w - mu) * rs * g.w + b.w;
    *(float4*)(out + (size_t)row * 256 + lane * 4) = o4;
}

// ---------------------------------------------------------------------------
extern "C" void kernel_launch(void* const* d_in, const int* in_sizes, int n_in,
                              void* d_out, int out_size, void* d_ws, size_t ws_size,
                              hipStream_t stream)
{
    const float* src     = (const float*)d_in[0];
    const float* refp    = (const float*)d_in[1];
    const float* w_value = (const float*)d_in[4];
    const float* b_value = (const float*)d_in[5];
    const float* w_off   = (const float*)d_in[6];
    const float* b_off   = (const float*)d_in[7];
    const float* w_attn  = (const float*)d_in[8];
    const float* b_attn  = (const float*)d_in[9];
    const float* w_out   = (const float*)d_in[10];
    const float* b_out   = (const float*)d_in[11];
    const float* gamma   = (const float*)d_in[12];
    const float* beta    = (const float*)d_in[13];

    char* ws = (char*)d_ws;
    ushort*   val_t    = (ushort*)  (ws);                   // 12,533,760 B
    float*    off_raw  = (float*)   (ws + 12533760);        // 25,067,520 B
    float*    attn_raw = (float*)   (ws + 37601280);        // 12,533,760 B
    uint32_t* sampled  = (uint32_t*)(ws + 37601280);        // alias of attn_raw (safe: K2)
    ushort*   B_pack   = (ushort*)  (ws + 50135040);        //    327,680 B
    ushort*   w_out_t  = (ushort*)  (ws + 50462720);        //    131,072 B
    float*    b_pack   = (float*)   (ws + 50593792);        //      2,560 B
    float*    x        = off_raw;                           // alias (off_raw dead after K2)
    float*    out      = (float*)d_out;

    conv_kernel<<<899, 256, 0, stream>>>(w_value, w_off, w_attn, b_value, b_off,
                                         b_attn, w_out, B_pack, w_out_t, b_pack);
    proj_gemm<<<dim3(383, 2), 256, 0, stream>>>(src, B_pack, b_pack, val_t,
                                                off_raw, attn_raw);
    sample_kernel<<<NQ * 8 / 16, 256, 0, stream>>>(refp, val_t, off_raw, attn_raw,
                                                   sampled);
    out_gemm<<<dim3(383, 2), 256, 0, stream>>>((const ushort*)sampled, w_out_t,
                                               b_out, src, x);
    ln_kernel<<<NQ / 4, 256, 0, stream>>>(x, gamma, beta, out);
}

// Round 4
// 246.718 us; speedup vs baseline: 2.1947x; 1.0674x over previous
//
#include <hip/hip_runtime.h>
#include <cstdint>
#include <cstddef>

#define D 256
#define HEADS 8
#define HD 32
#define NB 2
#define LQ 12240
#define NQ (NB * LQ)        // 24480
#define PLANE (LQ * HD)     // 391680 elements per (n,h) plane

typedef __attribute__((ext_vector_type(8))) short bf16x8;
typedef __attribute__((ext_vector_type(4))) float f32x4;
typedef __bf16 bf16x2 __attribute__((ext_vector_type(2)));

__device__ __forceinline__ ushort f2bf(float f) {
    union { float f; uint32_t u; } c; c.f = f;
    uint32_t u = c.u;
    uint32_t r = (u + 0x7fffu + ((u >> 16) & 1u)) >> 16;   // RNE, finite inputs
    return (ushort)r;
}

// c += a_pair . b_pair  (bf16 pairs packed in u32, f32 accumulate)
__device__ __forceinline__ float dot2bf(uint32_t a, uint32_t b, float c) {
#if __has_builtin(__builtin_amdgcn_fdot2_f32_bf16)
    return __builtin_amdgcn_fdot2_f32_bf16(__builtin_bit_cast(bf16x2, a),
                                           __builtin_bit_cast(bf16x2, b), c, false);
#else
    float alo = __uint_as_float(a << 16), ahi = __uint_as_float(a & 0xffff0000u);
    float blo = __uint_as_float(b << 16), bhi = __uint_as_float(b & 0xffff0000u);
    return c + alo * blo + ahi * bhi;
#endif
}

// ---------------------------------------------------------------------------
// K0: weight/bias conversion (unchanged).
// ---------------------------------------------------------------------------
__global__ __launch_bounds__(256) void conv_kernel(
    const float* __restrict__ w_value, const float* __restrict__ w_off,
    const float* __restrict__ w_attn,  const float* __restrict__ b_value,
    const float* __restrict__ b_off,   const float* __restrict__ b_attn,
    const float* __restrict__ w_out,
    ushort* __restrict__ B_pack, ushort* __restrict__ w_out_t,
    float* __restrict__ b_pack)
{
    const int b = blockIdx.x, k = threadIdx.x;
    if (b < 640) {
        float v;
        if (b < 256)      v = w_value[(size_t)k * 256 + b];
        else if (b < 512) v = w_off[(size_t)k * 256 + (b - 256)];
        else              v = w_attn[(size_t)k * 128 + (b - 512)];
        B_pack[(size_t)b * 256 + k] = f2bf(v);
    } else if (b < 896) {
        int n = b - 640;
        w_out_t[(size_t)n * 256 + k] = f2bf(w_out[(size_t)k * 256 + n]);
    } else if (b == 896) {
        b_pack[k] = b_value[k];
    } else if (b == 897) {
        b_pack[256 + k] = b_off[k];
    } else {
        if (k < 128) b_pack[512 + k] = b_attn[k];
    }
}

// ---------------------------------------------------------------------------
// K1: fused projections via MFMA (unchanged from R3).
// ---------------------------------------------------------------------------
__global__ __launch_bounds__(256) void proj_gemm(
    const float* __restrict__ src, const ushort* __restrict__ B_pack,
    const float* __restrict__ b_pack,
    ushort* __restrict__ val_t, float* __restrict__ off_raw,
    float* __restrict__ attn_raw)
{
    __shared__ ushort Abuf[64][264];
    __shared__ ushort Bbuf[64][264];
    const int tid = threadIdx.x;
    const int m0  = blockIdx.x * 64;

#pragma unroll
    for (int it = 0; it < 16; ++it) {
        int r = it * 4 + (tid >> 6), k4 = tid & 63;
        int row = m0 + r;
        float4 v = {0.f, 0.f, 0.f, 0.f};
        if (row < NQ) v = *(const float4*)(src + (size_t)row * 256 + k4 * 4);
        ushort4 o; o.x = f2bf(v.x); o.y = f2bf(v.y); o.z = f2bf(v.z); o.w = f2bf(v.w);
        *(ushort4*)&Abuf[r][k4 * 4] = o;
    }
    __syncthreads();

    const int wv = tid >> 6, lane = tid & 63;
    const int quad = lane >> 4, ln = lane & 15;

    bf16x8 af[8];
#pragma unroll
    for (int s = 0; s < 8; ++s)
        af[s] = *(const bf16x8*)&Abuf[wv * 16 + ln][s * 32 + quad * 8];

    for (int bi = 0; bi < 5; ++bi) {
        const int by = blockIdx.y * 5 + bi;
        __syncthreads();
#pragma unroll
        for (int it = 0; it < 16; ++it) {
            int n = it * 4 + (tid >> 6), kc = tid & 63;
            *(ushort4*)&Bbuf[n][kc * 4] =
                *(const ushort4*)(B_pack + ((size_t)(by * 64 + n)) * 256 + kc * 4);
        }
        __syncthreads();

        f32x4 acc[4] = {{0,0,0,0},{0,0,0,0},{0,0,0,0},{0,0,0,0}};
#pragma unroll
        for (int s = 0; s < 8; ++s) {
#pragma unroll
            for (int t = 0; t < 4; ++t) {
                bf16x8 bfr = *(const bf16x8*)&Bbuf[t * 16 + ln][s * 32 + quad * 8];
                acc[t] = __builtin_amdgcn_mfma_f32_16x16x32_bf16(af[s], bfr, acc[t], 0, 0, 0);
            }
        }

#pragma unroll
        for (int t = 0; t < 4; ++t) {
            int n_g = by * 64 + t * 16 + ln;
            float bias = b_pack[n_g];
#pragma unroll
            for (int reg = 0; reg < 4; ++reg) {
                int row = m0 + wv * 16 + quad * 4 + reg;
                if (row < NQ) {
                    float v = acc[t][reg] + bias;
                    if (n_g < 256) {
                        int h = n_g >> 5, hd = n_g & 31;
                        int nb = row >= LQ; int ql = row - nb * LQ;
                        val_t[(((size_t)(nb * 8 + h)) * LQ + ql) * 32 + hd] = f2bf(v);
                    } else if (n_g < 512) {
                        off_raw[(size_t)row * 256 + (n_g - 256)] = v;
                    } else {
                        attn_raw[(size_t)row * 128 + (n_g - 512)] = v;
                    }
                }
            }
        }
    }
}

// ---------------------------------------------------------------------------
// K1b: build x-pair table.  val_pair[plane][pos][c] = (v[pos][c], v[xnext][c])
// packed bf16x2 in u32, where xnext = pos+1 unless pos is at end of its row.
// One thread per u32 entry (6,266,880 total).
// ---------------------------------------------------------------------------
__global__ __launch_bounds__(256) void pair_kernel(
    const ushort* __restrict__ val_t, uint32_t* __restrict__ val_pair)
{
    const uint32_t i = blockIdx.x * 256 + threadIdx.x;   // < 6,266,880
    const uint32_t c = i & 31;
    const uint32_t rest = i >> 5;                        // plane*12240 + pos
    const uint32_t plane = rest / LQ;
    const uint32_t pos = rest - plane * LQ;
    // level boundaries: 9216, 11520, 12096
    int l = (pos >= 9216) + (pos >= 11520) + (pos >= 12096);
    uint32_t s0 = (l > 0 ? 9216u : 0u) + (l > 1 ? 2304u : 0u) + (l > 2 ? 576u : 0u);
    uint32_t Wi = 96u >> l;
    uint32_t p = pos - s0;
    uint32_t q = (p / 3u) >> (5 - l);          // p / Wi  (Wi = 3<<(5-l))
    uint32_t xr = p - q * Wi;                  // p % Wi
    uint32_t nxt = (xr == Wi - 1u) ? pos : pos + 1u;
    uint32_t lo = val_t[(size_t)plane * PLANE + pos * 32 + c];
    uint32_t hi = val_t[(size_t)plane * PLANE + nxt * 32 + c];
    val_pair[i] = lo | (hi << 16);
}

// ---------------------------------------------------------------------------
// K2: softmax + sampling + bilinear gather via x-pair table + dot2.
// 16-lane group per (n,q,head); setup lane = (level,point); per-point
// {idx0,idx1,wpack0,wpack1} staged to LDS (16B) and broadcast-read in the hot
// loop.  Hot loop/point: 1 ds_read_b128 + 2 dwordx2 gathers + 4 dot2.
// `sampled` aliases `attn_raw` word-exactly per lane -> safe.
// ---------------------------------------------------------------------------
__global__ __launch_bounds__(256) void sample_kernel(
    const float* __restrict__ ref_pts,
    const uint32_t* __restrict__ val_pair,
    const float* __restrict__ off_raw,
    const float* attn_raw,
    uint32_t* sampled)
{
    __shared__ uint4 sm[16][16];
    const int gl = threadIdx.x >> 4;
    const int ln = threadIdx.x & 15;
    const int g  = blockIdx.x * 16 + gl;
    const int qg = g >> 3, h = g & 7;
    const int n  = (qg >= LQ) ? 1 : 0;
    const int l  = ln >> 2;

    // softmax over 16 (level,point) logits of this head
    float a = attn_raw[(size_t)qg * 128 + h * 16 + ln];
    float m = a;
#pragma unroll
    for (int s = 8; s; s >>= 1) m = fmaxf(m, __shfl_xor(m, s, 16));
    float e = __expf(a - m);
    float ssum = e;
#pragma unroll
    for (int s = 8; s; s >>= 1) ssum += __shfl_xor(ssum, s, 16);
    float aw = e / ssum;

    float ox = off_raw[(size_t)qg * 256 + h * 32 + ln * 2 + 0];
    float oy = off_raw[(size_t)qg * 256 + h * 32 + ln * 2 + 1];
    float rx = ref_pts[(qg * 4 + l) * 2 + 0];
    float ry = ref_pts[(qg * 4 + l) * 2 + 1];

    const int Wi = 96 >> l;
    const int Hi = Wi;
    const int s0 = (l > 0 ? 9216 : 0) + (l > 1 ? 2304 : 0) + (l > 2 ? 576 : 0);
    const float Wf = (float)Wi, Hf = (float)Hi;

    float x = (rx + ox / Wf) * Wf - 0.5f;
    float y = (ry + oy / Hf) * Hf - 0.5f;
    float x0f = floorf(x), y0f = floorf(y);
    float lx = x - x0f, ly = y - y0f;
    int x0 = (int)x0f, y0 = (int)y0f;

    // row weights & clamped rows
    float wy0 = (y0 >= 0 && y0 < Hi) ? (1.f - ly) : 0.f;
    float wy1 = (y0 + 1 >= 0 && y0 + 1 < Hi) ? ly : 0.f;
    int yc0 = min(max(y0, 0), Hi - 1);
    int yc1 = min(max(y0 + 1, 0), Hi - 1);
    // x-pair weights: entry[xc] = (v[xc], v[xc+1 clamped])
    float wl = (x0 >= 0 && x0 < Wi) ? (1.f - lx) : 0.f;
    float wh = (x0 + 1 >= 0 && x0 + 1 < Wi) ? lx : 0.f;
    float pl, ph;
    int xe;
    if (x0 < 0) { pl = wh; ph = 0.f; xe = x0 + 1; }
    else        { pl = wl; ph = wh;  xe = x0; }
    int xc = min(max(xe, 0), Wi - 1);
    pl *= aw; ph *= aw;

    uint32_t wp0 = ((uint32_t)f2bf(ph * wy0) << 16) | (uint32_t)f2bf(pl * wy0);
    uint32_t wp1 = ((uint32_t)f2bf(ph * wy1) << 16) | (uint32_t)f2bf(pl * wy1);
    uint32_t idx0 = (uint32_t)(s0 + yc0 * Wi + xc) * 32u;
    uint32_t idx1 = (uint32_t)(s0 + yc1 * Wi + xc) * 32u;

    sm[gl][ln] = make_uint4(idx0, idx1, wp0, wp1);
    // intra-wave LDS write->read: compiler-inserted lgkmcnt orders it

    const uint32_t* plane =
        val_pair + (size_t)(n * HEADS + h) * PLANE + 2 * ln;
    float a0 = 0.f, a1 = 0.f;
#pragma unroll
    for (int p = 0; p < 16; ++p) {
        uint4 ent = sm[gl][p];
        uint2 r0 = *(const uint2*)(plane + ent.x);
        uint2 r1 = *(const uint2*)(plane + ent.y);
        a0 = dot2bf(r0.x, ent.z, a0);
        a1 = dot2bf(r0.y, ent.z, a1);
        a0 = dot2bf(r1.x, ent.w, a0);
        a1 = dot2bf(r1.y, ent.w, a1);
    }
    uint32_t r = ((uint32_t)f2bf(a1) << 16) | (uint32_t)f2bf(a0);
    sampled[(size_t)qg * 128 + h * 16 + ln] = r;
}

// ---------------------------------------------------------------------------
// K3: fused out-proj + residual + LayerNorm.  Each block: 64 rows, all 256
// cols (4 N-tiles kept in registers: 64 acc f32/thread).  LN stats via
// width-16 shuffles (each wave owns 16 full rows).  Writes final output.
// ---------------------------------------------------------------------------
__global__ __launch_bounds__(256) void out_ln_gemm(
    const ushort* __restrict__ sampled, const ushort* __restrict__ w_out_t,
    const float* __restrict__ b_out,    const float* __restrict__ src,
    const float* __restrict__ gamma,    const float* __restrict__ beta,
    float* __restrict__ out)
{
    __shared__ ushort Abuf[64][264];
    __shared__ ushort Bbuf[64][264];
    __shared__ float gb[256], bb[256], bob[256];
    const int tid = threadIdx.x;
    const int m0  = blockIdx.x * 64;

    gb[tid]  = gamma[tid];
    bb[tid]  = beta[tid];
    bob[tid] = b_out[tid];

#pragma unroll
    for (int it = 0; it < 16; ++it) {
        int r = it * 4 + (tid >> 6), kc = tid & 63;
        int row = m0 + r;
        ushort4 v = {0, 0, 0, 0};
        if (row < NQ) v = *(const ushort4*)(sampled + (size_t)row * 256 + kc * 4);
        *(ushort4*)&Abuf[r][kc * 4] = v;
    }
    __syncthreads();

    const int wv = tid >> 6, lane = tid & 63;
    const int quad = lane >> 4, ln = lane & 15;

    bf16x8 af[8];
#pragma unroll
    for (int s = 0; s < 8; ++s)
        af[s] = *(const bf16x8*)&Abuf[wv * 16 + ln][s * 32 + quad * 8];

    f32x4 acc[4][4];
#pragma unroll
    for (int by = 0; by < 4; ++by)
#pragma unroll
        for (int t = 0; t < 4; ++t) acc[by][t] = (f32x4){0, 0, 0, 0};

#pragma unroll
    for (int by = 0; by < 4; ++by) {
        __syncthreads();
#pragma unroll
        for (int it = 0; it < 16; ++it) {
            int nn = it * 4 + (tid >> 6), kc = tid & 63;
            *(ushort4*)&Bbuf[nn][kc * 4] =
                *(const ushort4*)(w_out_t + ((size_t)(by * 64 + nn)) * 256 + kc * 4);
        }
        __syncthreads();
#pragma unroll
        for (int s = 0; s < 8; ++s) {
#pragma unroll
            for (int t = 0; t < 4; ++t) {
                bf16x8 bfr = *(const bf16x8*)&Bbuf[t * 16 + ln][s * 32 + quad * 8];
                acc[by][t] = __builtin_amdgcn_mfma_f32_16x16x32_bf16(af[s], bfr, acc[by][t], 0, 0, 0);
            }
        }
    }

    // epilogue: residual + bias, LN stats per row (16 cols/thread, x16 lanes)
#pragma unroll
    for (int reg = 0; reg < 4; ++reg) {
        const int row = m0 + wv * 16 + quad * 4 + reg;
        float xv[16];
        float s = 0.f, s2 = 0.f;
#pragma unroll
        for (int bt = 0; bt < 16; ++bt) {
            int col = bt * 16 + ln;
            float v = acc[bt >> 2][bt & 3][reg] + bob[col];
            if (row < NQ) v += src[(size_t)row * 256 + col];
            xv[bt] = v;
            s += v; s2 += v * v;
        }
#pragma unroll
        for (int o = 8; o; o >>= 1) {
            s  += __shfl_xor(s, o, 16);
            s2 += __shfl_xor(s2, o, 16);
        }
        float mu  = s * (1.f / 256.f);
        float var = s2 * (1.f / 256.f) - mu * mu;
        float rs  = rsqrtf(var + 1e-5f);
        if (row < NQ) {
#pragma unroll
            for (int bt = 0; bt < 16; ++bt) {
                int col = bt * 16 + ln;
                out[(size_t)row * 256 + col] = (xv[bt] - mu) * rs * gb[col] + bb[col];
            }
        }
    }
}

// ---------------------------------------------------------------------------
extern "C" void kernel_launch(void* const* d_in, const int* in_sizes, int n_in,
                              void* d_out, int out_size, void* d_ws, size_t ws_size,
                              hipStream_t stream)
{
    const float* src     = (const float*)d_in[0];
    const float* refp    = (const float*)d_in[1];
    const float* w_value = (const float*)d_in[4];
    const float* b_value = (const float*)d_in[5];
    const float* w_off   = (const float*)d_in[6];
    const float* b_off   = (const float*)d_in[7];
    const float* w_attn  = (const float*)d_in[8];
    const float* b_attn  = (const float*)d_in[9];
    const float* w_out   = (const float*)d_in[10];
    const float* b_out   = (const float*)d_in[11];
    const float* gamma   = (const float*)d_in[12];
    const float* beta    = (const float*)d_in[13];

    char* ws = (char*)d_ws;
    ushort*   val_t    = (ushort*)  (ws);                   // 12,533,760 B
    uint32_t* val_pair = (uint32_t*)(ws + 12533760);        // 25,067,520 B
    float*    off_raw  = (float*)   (ws + 37601280);        // 25,067,520 B
    float*    attn_raw = (float*)   (ws + 62668800);        // 12,533,760 B
    uint32_t* sampled  = (uint32_t*)(ws + 62668800);        // alias of attn_raw (safe: K2)
    ushort*   B_pack   = (ushort*)  (ws + 75202560);        //    327,680 B
    ushort*   w_out_t  = (ushort*)  (ws + 75530240);        //    131,072 B
    float*    b_pack   = (float*)   (ws + 75661312);        //      2,560 B
    float*    out      = (float*)d_out;

    conv_kernel<<<899, 256, 0, stream>>>(w_value, w_off, w_attn, b_value, b_off,
                                         b_attn, w_out, B_pack, w_out_t, b_pack);
    proj_gemm<<<dim3(383, 2), 256, 0, stream>>>(src, B_pack, b_pack, val_t,
                                                off_raw, attn_raw);
    pair_kernel<<<24480, 256, 0, stream>>>(val_t, val_pair);
    sample_kernel<<<12240, 256, 0, stream>>>(refp, val_pair, off_raw, attn_raw,
                                             sampled);
    out_ln_gemm<<<383, 256, 0, stream>>>((const ushort*)sampled, w_out_t, b_out,
                                         src, gamma, beta, out);
}